// Round 12
// baseline (1738.897 us; speedup 1.0000x reference)
//
#include <hip/hip_runtime.h>

typedef int      i32x4 __attribute__((ext_vector_type(4)));
typedef float    f32x4 __attribute__((ext_vector_type(4)));
typedef unsigned u32x2 __attribute__((ext_vector_type(2)));

#define RNN_H 128
#define RNN_T 2048
#define RNN_B 8192
#define RNN_C 10
#define BLK_N 32                // two 16-col tiles (A, B) per block, per wave
#define QSW 32512.0f            // 127*256: fixed-point scale for W and h
#define K2E 2.885390081777927f  // 2*log2(e), folded into kk/wx/bh

// LDS-only barrier: drain ds ops, never vmcnt (x prefetch stays in flight).
#define BAR() asm volatile("s_waitcnt lgkmcnt(0)\n\ts_barrier" ::: "memory")
#define SBAR() __builtin_amdgcn_sched_barrier(0)

__device__ __forceinline__ i32x4 mfma_i8(i32x4 a, i32x4 b, i32x4 c) {
  return __builtin_amdgcn_mfma_i32_16x16x64_i8(a, b, c, 0, 0, 0);
}

// k-bijection for 16x16x64 i8 frags (byte p of the 4-dword operand, lane
// group g = lane>>4): k = 64*slot + 4g + (p&3) + 16*jg(p>>2). Per-wave jg
// permutation puts the own-half j-groups at frag dwords 0,1 (A-fill permuted
// identically, so sum over k unchanged) -> register recycle without muxes.
// h = q/32512, q = 256a + b; W row-scaled 15-bit -> (wa, wb) int8 pairs.
// X = 256*P1 + P23, P1 = S wa*a, P23 = S(wa*b + wb*a) (wb*b dropped ~2e-5).
//
// Dual-tile in-wave pipeline (tile B one half-step ahead):
//  P1(t): dsread A-partners; MFMA_A = W.h_A(t); [SBAR] epi_B: pB,x_B(t) ->
//         h_B(t+1) frags + LDS write; BAR.
//  P2(t): dsread B-partners; MFMA_B = W.h_B(t+1); [SBAR] epi_A: pA,x_A(t) ->
//         h_A(t+1) frags + LDS write; BAR.
// epi_Y's MFMA inputs completed a full phase ago -> its VALU overlaps
// MFMA_X's grind, in-order, within one wave. 1 wave/SIMD: pipes are private.

__global__ __launch_bounds__(256, 1)
void rnn_fused(const float* __restrict__ x, const float* __restrict__ w_hx,
               const float* __restrict__ w_hh, const float* __restrict__ b_h,
               const float* __restrict__ w_ph, const float* __restrict__ b_p,
               float* __restrict__ out)
{
  // single buffer per tile: [tile][slot(2)][part a/b][half(2)][lane] = 8 KiB
  __shared__ u32x2 hbuf[2][2][2][2][64];
  __shared__ float rs[128];

  const int tid  = threadIdx.x;
  const int lane = tid & 63;
  const int wv   = tid >> 6;       // 0..3: rows [32wv, 32wv+32)
  const int g    = lane >> 4;
  const int l15  = lane & 15;
  const int n0   = blockIdx.x * BLK_N;
  const int sw = wv >> 1, hw = wv & 1, so = sw ^ 1;

  { // zero h(0) for both tiles (1024 u32x2 entries)
    u32x2 z = {0u, 0u};
    u32x2* p = &hbuf[0][0][0][0][0];
    p[tid] = z; p[tid+256] = z; p[tid+512] = z; p[tid+768] = z;
  }

  // ---- W quantization (shared by both tiles): per-row 15-bit, int8 split.
  i32x4 WA[2][2], WB[2][2];   // [mt][0 = own slot (jg-permuted), 1 = other]
  float rm[2];
  #pragma unroll
  for (int mt = 0; mt < 2; ++mt) {
    const float* wrow = w_hh + (size_t)(wv*32 + mt*16 + l15)*RNN_H + 4*g;
    float vals[2][4][4];
    float mx = 0.0f;
    #pragma unroll
    for (int li = 0; li < 2; ++li) {
      const int s = li ? so : sw;
      #pragma unroll
      for (int d = 0; d < 4; ++d) {
        const int jg = li ? d : ((d < 2) ? (2*hw + d) : (2*(hw^1) + (d-2)));
        f32x4 v = *(const f32x4*)(wrow + s*64 + jg*16);
        #pragma unroll
        for (int r = 0; r < 4; ++r) { vals[li][d][r] = v[r]; mx = fmaxf(mx, fabsf(v[r])); }
      }
    }
    mx = fmaxf(mx, __shfl_xor(mx, 16));
    mx = fmaxf(mx, __shfl_xor(mx, 32));
    const float inv = (mx > 0.0f) ? (QSW / mx) : 0.0f;
    rm[mt] = mx * (1.0f / QSW);
    #pragma unroll
    for (int li = 0; li < 2; ++li)
      #pragma unroll
      for (int d = 0; d < 4; ++d) {
        unsigned pa = 0, pb = 0;
        #pragma unroll
        for (int r = 0; r < 4; ++r) {
          const int Wq  = (int)rintf(vals[li][d][r] * inv);
          const int wa  = (Wq + 128) >> 8;
          const int wbv = Wq - (wa << 8);
          pa |= ((unsigned)(wa  & 255)) << (8*r);
          pb |= ((unsigned)(wbv & 255)) << (8*r);
        }
        WA[mt][li][d] = (int)pa;
        WB[mt][li][d] = (int)pb;
      }
  }

  if (g == 0) {
    rs[wv*32 +  0 + l15] = rm[0];
    rs[wv*32 + 16 + l15] = rm[1];
  }
  __syncthreads();

  f32x4 kk2[2], wx2[2], bh2[2];
  #pragma unroll
  for (int mt = 0; mt < 2; ++mt)
    #pragma unroll
    for (int r = 0; r < 4; ++r) {
      const int m = wv*32 + mt*16 + 4*g + r;
      kk2[mt][r] = rs[m] * (K2E / 127.0f);
      wx2[mt][r] = w_hx[m] * K2E;
      bh2[mt][r] = b_h[m] * K2E;
    }

  const float* pxA = x + (size_t)(n0 + l15) * RNN_T;
  const float* pxB = x + (size_t)(n0 + 16 + l15) * RNN_T;
  f32x4 xcA = *(const f32x4*)pxA;
  f32x4 xcB = *(const f32x4*)pxB;

  const i32x4 ZI = {0,0,0,0};
  // own frags per tile (h(0) = 0) and accumulators (B primed to 0)
  u32x2 oAa = {0u,0u}, oAb = {0u,0u}, oBa = {0u,0u}, oBb = {0u,0u};
  i32x4 pA1[2], pA23[2], pB1[2], pB23[2];
  #pragma unroll
  for (int mt = 0; mt < 2; ++mt) { pB1[mt] = ZI; pB23[mt] = ZI; }

  const unsigned c0080 = 0x00800080u;
  const unsigned selA  = 0x07050301u;
  const unsigned selB  = 0x06040200u;
  const float TPP = 32512.0f / 32767.0f;
  const float TPN = -2.0f * TPP;

  __syncthreads();

  // MFMA phase for tile TI: LDS partner reads + 12 i8 MFMAs into Pd/Pe.
  auto do_mfma = [&](int TI, const u32x2& ofa, const u32x2& ofb,
                     i32x4* Pd, i32x4* Pe) {
    const u32x2 poA = hbuf[TI][sw][0][hw^1][lane];
    const u32x2 poB = hbuf[TI][sw][1][hw^1][lane];
    const u32x2 oa0 = hbuf[TI][so][0][0][lane];
    const u32x2 oa1 = hbuf[TI][so][0][1][lane];
    const u32x2 ob0 = hbuf[TI][so][1][0][lane];
    const u32x2 ob1 = hbuf[TI][so][1][1][lane];
    const i32x4 FaOwn = {(int)ofa[0], (int)ofa[1], (int)poA[0], (int)poA[1]};
    const i32x4 FbOwn = {(int)ofb[0], (int)ofb[1], (int)poB[0], (int)poB[1]};
    const i32x4 FaOth = {(int)oa0[0], (int)oa0[1], (int)oa1[0], (int)oa1[1]};
    const i32x4 FbOth = {(int)ob0[0], (int)ob0[1], (int)ob1[0], (int)ob1[1]};
    Pd[0] = mfma_i8(WA[0][0], FaOwn, ZI);
    Pd[1] = mfma_i8(WA[1][0], FaOwn, ZI);
    Pe[0] = mfma_i8(WB[0][0], FaOwn, ZI);
    Pe[1] = mfma_i8(WB[1][0], FaOwn, ZI);
    Pe[0] = mfma_i8(WA[0][0], FbOwn, Pe[0]);
    Pe[1] = mfma_i8(WA[1][0], FbOwn, Pe[1]);
    Pd[0] = mfma_i8(WA[0][1], FaOth, Pd[0]);
    Pd[1] = mfma_i8(WA[1][1], FaOth, Pd[1]);
    Pe[0] = mfma_i8(WB[0][1], FaOth, Pe[0]);
    Pe[1] = mfma_i8(WB[1][1], FaOth, Pe[1]);
    Pe[0] = mfma_i8(WA[0][1], FbOth, Pe[0]);
    Pe[1] = mfma_i8(WA[1][1], FbOth, Pe[1]);
  };

  // epilogue for tile TI: consume Pd/Pe (completed a phase ago) + xv ->
  // new own frags + LDS publish.
  auto do_epi = [&](int TI, const i32x4* Pd, const i32x4* Pe, float xv,
                    u32x2& ofa, u32x2& ofb) {
    unsigned napk[2], nbpk[2];
    #pragma unroll
    for (int mt = 0; mt < 2; ++mt) {
      float tp0, tp1, tp2, tp3;
      {
        const int X0 = (Pd[mt][0] << 8) + Pe[mt][0];
        const int X1 = (Pd[mt][1] << 8) + Pe[mt][1];
        const int X2 = (Pd[mt][2] << 8) + Pe[mt][2];
        const int X3 = (Pd[mt][3] << 8) + Pe[mt][3];
        const float v0 = __builtin_fmaf(kk2[mt][0], (float)X0,
                           __builtin_fmaf(wx2[mt][0], xv, bh2[mt][0]));
        const float v1 = __builtin_fmaf(kk2[mt][1], (float)X1,
                           __builtin_fmaf(wx2[mt][1], xv, bh2[mt][1]));
        const float v2 = __builtin_fmaf(kk2[mt][2], (float)X2,
                           __builtin_fmaf(wx2[mt][2], xv, bh2[mt][2]));
        const float v3 = __builtin_fmaf(kk2[mt][3], (float)X3,
                           __builtin_fmaf(wx2[mt][3], xv, bh2[mt][3]));
        const float e0 = __builtin_amdgcn_exp2f(v0);
        const float e1 = __builtin_amdgcn_exp2f(v1);
        const float e2 = __builtin_amdgcn_exp2f(v2);
        const float e3 = __builtin_amdgcn_exp2f(v3);
        const float r0 = __builtin_amdgcn_rcpf(e0 + 1.0f);
        const float r1 = __builtin_amdgcn_rcpf(e1 + 1.0f);
        const float r2 = __builtin_amdgcn_rcpf(e2 + 1.0f);
        const float r3 = __builtin_amdgcn_rcpf(e3 + 1.0f);
        tp0 = __builtin_fmaf(r0, TPN, TPP);
        tp1 = __builtin_fmaf(r1, TPN, TPP);
        tp2 = __builtin_fmaf(r2, TPN, TPP);
        tp3 = __builtin_fmaf(r3, TPN, TPP);
      }
      unsigned q01, q23, a01, a23, pa, pb;
      asm("v_cvt_pknorm_i16_f32 %0, %1, %2" : "=v"(q01) : "v"(tp0), "v"(tp1));
      asm("v_cvt_pknorm_i16_f32 %0, %1, %2" : "=v"(q23) : "v"(tp2), "v"(tp3));
      asm("v_pk_add_i16 %0, %1, %2" : "=v"(a01) : "v"(q01), "v"(c0080));
      asm("v_pk_add_i16 %0, %1, %2" : "=v"(a23) : "v"(q23), "v"(c0080));
      asm("v_perm_b32 %0, %1, %2, %3" : "=v"(pa) : "v"(a23), "v"(a01), "v"(selA));
      asm("v_perm_b32 %0, %1, %2, %3" : "=v"(pb) : "v"(q23), "v"(q01), "v"(selB));
      napk[mt] = pa; nbpk[mt] = pb;
    }
    ofa = u32x2{napk[0], napk[1]};
    ofb = u32x2{nbpk[0], nbpk[1]};
    hbuf[TI][sw][0][hw][lane] = ofa;
    hbuf[TI][sw][1][hw][lane] = ofb;
  };

  for (int t4 = 0; t4 < RNN_T/4; ++t4) {
    f32x4 xnA = xcA, xnB = xcB;
    if (t4 + 1 < RNN_T/4) {
      xnA = *(const f32x4*)(pxA + 4*t4 + 4);
      xnB = *(const f32x4*)(pxB + 4*t4 + 4);
    }
    #pragma unroll
    for (int qq = 0; qq < 4; ++qq) {
      // P1: MFMA_A(t) grinds while epi_B finishes h_B(t+1)
      do_mfma(0, oAa, oAb, pA1, pA23);
      SBAR();
      do_epi(1, pB1, pB23, xcB[qq], oBa, oBb);
      BAR();
      // P2: MFMA_B(t+1) grinds while epi_A finishes h_A(t+1)
      do_mfma(1, oBa, oBb, pB1, pB23);
      SBAR();
      do_epi(0, pA1, pA23, xcA[qq], oAa, oAb);
      BAR();
    }
    xcA = xnA; xcB = xnB;
  }

  __syncthreads();

  // ---- projection: out[b][c] = w_ph[c,:] . h_last[:,b] + b_p[c] ----
  // h_A(T) in hbuf[0], h_B(T) in hbuf[1]; h = (256*a + b)/32512.
  #pragma unroll
  for (int pass = 0; pass < 2; ++pass) {
    const int idx = tid + pass*256;
    const int c   = idx >> 5;
    const int n32 = idx & 31;
    if (c < RNN_C) {
      const int tile = n32 >> 4;
      const int n    = n32 & 15;
      float sum = b_p[c];
      for (int k = 0; k < RNN_H; ++k) {
        const int s  = k >> 6;
        const int ko = k & 63;
        const int g2 = (ko >> 2) & 3;
        const int j  = (ko & 3) + 4*(ko >> 4);
        const int half = j >> 3, jj = j & 7;
        const signed char* pa = (const signed char*)&hbuf[tile][s][0][half][16*g2 + n];
        const signed char* pb = (const signed char*)&hbuf[tile][s][1][half][16*g2 + n];
        const int qv = 256*(int)pa[jj] + (int)pb[jj];
        sum = __builtin_fmaf(w_ph[c*RNN_H + k], qv * (1.0f/QSW), sum);
      }
      out[(size_t)(n0 + n32)*RNN_C + c] = sum;
    }
  }
}

extern "C" void kernel_launch(void* const* d_in, const int* in_sizes, int n_in,
                              void* d_out, int out_size, void* d_ws, size_t ws_size,
                              hipStream_t stream) {
  (void)in_sizes; (void)n_in; (void)out_size; (void)d_ws; (void)ws_size;
  const float* x    = (const float*)d_in[0];
  const float* w_hx = (const float*)d_in[1];
  const float* w_hh = (const float*)d_in[2];
  const float* b_h  = (const float*)d_in[3];
  const float* w_ph = (const float*)d_in[4];
  const float* b_p  = (const float*)d_in[5];
  float* out = (float*)d_out;
  rnn_fused<<<dim3(RNN_B/BLK_N), dim3(256), 0, stream>>>(x, w_hx, w_hh, b_h, w_ph, b_p, out);
}

// Round 13
// 1056.406 us; speedup vs baseline: 1.6461x; 1.6461x over previous
//
#include <hip/hip_runtime.h>

typedef int      i32x4 __attribute__((ext_vector_type(4)));
typedef float    f32x4 __attribute__((ext_vector_type(4)));
typedef unsigned u32x2 __attribute__((ext_vector_type(2)));
typedef unsigned u32x4 __attribute__((ext_vector_type(4)));

#define RNN_H 128
#define RNN_T 2048
#define RNN_B 8192
#define RNN_C 10
#define BLK_N 16
#define QSW 32512.0f            // 127*256: fixed-point scale for W and h
#define K2E 2.885390081777927f  // 2*log2(e), folded into kk/wx/bh

// LDS-only barrier: drain ds ops, never vmcnt (x prefetch stays in flight).
#define BAR() asm volatile("s_waitcnt lgkmcnt(0)\n\ts_barrier" ::: "memory")
#define MEMPIN() asm volatile("" ::: "memory")

__device__ __forceinline__ i32x4 mfma_i8(i32x4 a, i32x4 b, i32x4 c) {
  return __builtin_amdgcn_mfma_i32_16x16x64_i8(a, b, c, 0, 0, 0);
}

// k-bijection for 16x16x64 i8 frags (byte p of the 4-dword operand, lane
// group g = lane>>4): k = 64*slot + 4g + (p&3) + 16*jg(p>>2). Per-wave jg
// permutation puts the own-half j-groups at frag dwords 0,1 (A-fill permuted
// identically, so sum over k is unchanged) -> register recycle, no muxes.
// h = q/32512, q = 256a + b; W row-scaled 15-bit -> (wa, wb) int8 pairs.
// X = 256*P1 + P23, P1 = S wa*a, P23 = S(wa*b + wb*a) (wb*b dropped ~2e-5).
// LDS layout (b128-merged): [buf][slot][half][lane] u32x4, bytes 0-7 = a-part,
// 8-15 = b-part. Per wave-step: 3 x ds_read_b128 + 1 x ds_write_b128.

__global__ __launch_bounds__(256, 2)
void rnn_fused(const float* __restrict__ x, const float* __restrict__ w_hx,
               const float* __restrict__ w_hh, const float* __restrict__ b_h,
               const float* __restrict__ w_ph, const float* __restrict__ b_p,
               float* __restrict__ out)
{
  // h double-buffered: [buf][slot(2)][half(2)][lane(64)] x 16B = 8 KiB
  __shared__ u32x4 hbuf[2][2][2][64];
  __shared__ float rs[128];   // per-row W scales for C/D-lane redistribution

  const int tid  = threadIdx.x;
  const int lane = tid & 63;
  const int wv   = tid >> 6;       // 0..3: rows [32wv, 32wv+32)
  const int g    = lane >> 4;
  const int l15  = lane & 15;
  const int n0   = blockIdx.x * BLK_N;
  const int sw = wv >> 1, hw = wv & 1, so = sw ^ 1;

  { // zero h(0) = buffer 0 (512 u32x4 entries)
    u32x4 z = {0u, 0u, 0u, 0u};
    u32x4* p = &hbuf[0][0][0][0];
    p[tid] = z; p[tid + 256] = z;
  }

  // ---- W quantization: per-row 15-bit fixed point, split to int8 (wa, wb).
  // li = 0: own slot with per-wave jg permutation; li = 1: other slot natural.
  i32x4 WA[2][2], WB[2][2];
  float rm[2];
  #pragma unroll
  for (int mt = 0; mt < 2; ++mt) {
    const float* wrow = w_hh + (size_t)(wv*32 + mt*16 + l15)*RNN_H + 4*g;
    float vals[2][4][4];
    float mx = 0.0f;
    #pragma unroll
    for (int li = 0; li < 2; ++li) {
      const int s = li ? so : sw;
      #pragma unroll
      for (int d = 0; d < 4; ++d) {
        const int jg = li ? d : ((d < 2) ? (2*hw + d) : (2*(hw^1) + (d-2)));
        f32x4 v = *(const f32x4*)(wrow + s*64 + jg*16);
        #pragma unroll
        for (int r = 0; r < 4; ++r) { vals[li][d][r] = v[r]; mx = fmaxf(mx, fabsf(v[r])); }
      }
    }
    mx = fmaxf(mx, __shfl_xor(mx, 16));   // combine the 4 g-lanes of this row
    mx = fmaxf(mx, __shfl_xor(mx, 32));
    const float inv = (mx > 0.0f) ? (QSW / mx) : 0.0f;
    rm[mt] = mx * (1.0f / QSW);
    #pragma unroll
    for (int li = 0; li < 2; ++li)
      #pragma unroll
      for (int d = 0; d < 4; ++d) {
        unsigned pa = 0, pb = 0;
        #pragma unroll
        for (int r = 0; r < 4; ++r) {
          const int Wq  = (int)rintf(vals[li][d][r] * inv);  // |Wq| <= 32512
          const int wa  = (Wq + 128) >> 8;                   // [-127, 127]
          const int wbv = Wq - (wa << 8);                    // [-128, 127]
          pa |= ((unsigned)(wa  & 255)) << (8*r);
          pb |= ((unsigned)(wbv & 255)) << (8*r);
        }
        WA[mt][li][d] = (int)pa;
        WB[mt][li][d] = (int)pb;
      }
  }

  if (g == 0) {                       // publish row scales (rows 32wv+16mt+l15)
    rs[wv*32 +  0 + l15] = rm[0];
    rs[wv*32 + 16 + l15] = rm[1];
  }
  __syncthreads();

  // per-C/D-reg constants (K2E folded): m = 32wv + 16mt + 4g + r
  f32x4 kk2[2], wx2[2], bh2[2];
  #pragma unroll
  for (int mt = 0; mt < 2; ++mt)
    #pragma unroll
    for (int r = 0; r < 4; ++r) {
      const int m = wv*32 + mt*16 + 4*g + r;
      kk2[mt][r] = rs[m] * (K2E / 127.0f);
      wx2[mt][r] = w_hx[m] * K2E;
      bh2[mt][r] = b_h[m] * K2E;
    }

  const float* px = x + (size_t)(n0 + l15) * RNN_T;
  f32x4 xc = *(const f32x4*)px;

  const i32x4 ZI = {0,0,0,0};
  u32x2 ownA = {0u,0u}, ownB = {0u,0u};   // own half frags (h(0) = 0)

  // epilogue constants (VGPR-resident; v_perm/v_pk_add take no literals)
  const unsigned c0080 = 0x00800080u;   // +128 per i16 (a-byte rounding)
  const unsigned selA  = 0x07050301u;   // a-bytes: bytes 1,3 of each i16 pair
  const unsigned selB  = 0x06040200u;   // b-bytes: bytes 0,2
  const float TPP = 32512.0f / 32767.0f;  // pknorm prescale -> q = rint(t*32512)
  const float TPN = -2.0f * TPP;

  __syncthreads();

  // anti-phase stagger: the two co-resident blocks per CU are most likely
  // (b, b+256); delay the second dispatch round by ~half a step (~600 cy of
  // dependent FMAs) so its epi phase overlaps our MFMA phase. One-time cost.
  if (blockIdx.x >= 256) {
    float acc = (float)lane;
    #pragma unroll 1
    for (int i = 0; i < 150; ++i) acc = __builtin_fmaf(acc, 0.9999f, 1.0f);
    if (acc == 12345.678f) rs[0] = acc;   // unreachable; keeps loop alive
  }

  for (int t4 = 0; t4 < RNN_T/4; ++t4) {
    f32x4 xn = xc;
    if (t4 + 1 < RNN_T/4) xn = *(const f32x4*)(px + 4*t4 + 4);
    #pragma unroll
    for (int qq = 0; qq < 4; ++qq) {
      const int rb = qq & 1, wb2 = rb ^ 1;
      const float xv = xc[qq];

      // 3 x ds_read_b128 (conflict-free): partner half first (feeds MFMA #1)
      const u32x4 RH = hbuf[rb][sw][hw^1][lane];   // own slot, partner half
      const u32x4 R0 = hbuf[rb][so][0][lane];      // other slot, half 0
      const u32x4 R1 = hbuf[rb][so][1][lane];      // other slot, half 1
      MEMPIN();

      // static fragment assembly (no muxes; own half always dwords 0,1)
      const i32x4 FaOwn = {(int)ownA[0], (int)ownA[1], (int)RH[0], (int)RH[1]};
      const i32x4 FbOwn = {(int)ownB[0], (int)ownB[1], (int)RH[2], (int)RH[3]};
      const i32x4 FaOth = {(int)R0[0], (int)R0[1], (int)R1[0], (int)R1[1]};
      const i32x4 FbOth = {(int)R0[2], (int)R0[3], (int)R1[2], (int)R1[3]};

      // 12 i8 MFMAs, 4 chains (P1 x2 depth 2, P23 x2 depth 4)
      i32x4 P1[2], P23[2];
      __builtin_amdgcn_s_setprio(1);
      P1[0]  = mfma_i8(WA[0][0], FaOwn, ZI);
      P1[1]  = mfma_i8(WA[1][0], FaOwn, ZI);
      P23[0] = mfma_i8(WB[0][0], FaOwn, ZI);
      P23[1] = mfma_i8(WB[1][0], FaOwn, ZI);
      P23[0] = mfma_i8(WA[0][0], FbOwn, P23[0]);
      P23[1] = mfma_i8(WA[1][0], FbOwn, P23[1]);
      P1[0]  = mfma_i8(WA[0][1], FaOth, P1[0]);
      P1[1]  = mfma_i8(WA[1][1], FaOth, P1[1]);
      P23[0] = mfma_i8(WB[0][1], FaOth, P23[0]);
      P23[1] = mfma_i8(WB[1][1], FaOth, P23[1]);
      P23[0] = mfma_i8(WA[0][1], FbOth, P23[0]);
      P23[1] = mfma_i8(WA[1][1], FbOth, P23[1]);
      __builtin_amdgcn_s_setprio(0);

      // epilogue: X -> tanh (exp2+rcp) -> pknorm i16 -> byte split via perm
      unsigned napk[2], nbpk[2];
      #pragma unroll
      for (int mt = 0; mt < 2; ++mt) {
        float tp0, tp1, tp2, tp3;
        {
          const int X0 = (P1[mt][0] << 8) + P23[mt][0];
          const int X1 = (P1[mt][1] << 8) + P23[mt][1];
          const int X2 = (P1[mt][2] << 8) + P23[mt][2];
          const int X3 = (P1[mt][3] << 8) + P23[mt][3];
          const float v0 = __builtin_fmaf(kk2[mt][0], (float)X0,
                             __builtin_fmaf(wx2[mt][0], xv, bh2[mt][0]));
          const float v1 = __builtin_fmaf(kk2[mt][1], (float)X1,
                             __builtin_fmaf(wx2[mt][1], xv, bh2[mt][1]));
          const float v2 = __builtin_fmaf(kk2[mt][2], (float)X2,
                             __builtin_fmaf(wx2[mt][2], xv, bh2[mt][2]));
          const float v3 = __builtin_fmaf(kk2[mt][3], (float)X3,
                             __builtin_fmaf(wx2[mt][3], xv, bh2[mt][3]));
          const float e0 = __builtin_amdgcn_exp2f(v0);
          const float e1 = __builtin_amdgcn_exp2f(v1);
          const float e2 = __builtin_amdgcn_exp2f(v2);
          const float e3 = __builtin_amdgcn_exp2f(v3);
          const float r0 = __builtin_amdgcn_rcpf(e0 + 1.0f);
          const float r1 = __builtin_amdgcn_rcpf(e1 + 1.0f);
          const float r2 = __builtin_amdgcn_rcpf(e2 + 1.0f);
          const float r3 = __builtin_amdgcn_rcpf(e3 + 1.0f);
          tp0 = __builtin_fmaf(r0, TPN, TPP);
          tp1 = __builtin_fmaf(r1, TPN, TPP);
          tp2 = __builtin_fmaf(r2, TPN, TPP);
          tp3 = __builtin_fmaf(r3, TPN, TPP);
        }
        unsigned q01, q23, a01, a23, pa, pb;
        asm("v_cvt_pknorm_i16_f32 %0, %1, %2" : "=v"(q01) : "v"(tp0), "v"(tp1));
        asm("v_cvt_pknorm_i16_f32 %0, %1, %2" : "=v"(q23) : "v"(tp2), "v"(tp3));
        asm("v_pk_add_i16 %0, %1, %2" : "=v"(a01) : "v"(q01), "v"(c0080));
        asm("v_pk_add_i16 %0, %1, %2" : "=v"(a23) : "v"(q23), "v"(c0080));
        asm("v_perm_b32 %0, %1, %2, %3" : "=v"(pa) : "v"(a23), "v"(a01), "v"(selA));
        asm("v_perm_b32 %0, %1, %2, %3" : "=v"(pb) : "v"(q23), "v"(q01), "v"(selB));
        napk[mt] = pa; nbpk[mt] = pb;
      }
      ownA = u32x2{napk[0], napk[1]};
      ownB = u32x2{nbpk[0], nbpk[1]};

      // publish own half: single ds_write_b128 (a-part dwords 0-1, b 2-3)
      hbuf[wb2][sw][hw][lane] = u32x4{napk[0], napk[1], nbpk[0], nbpk[1]};
      BAR();
    }
    xc = xn;
  }

  __syncthreads();

  // ---- projection: out[b][c] = w_ph[c,:] . h_last[:,b] + b_p[c] ----
  // t=2047 wrote buffer 0; h = (256*a + b) / 32512.
  {
    const int c = tid >> 4;
    const int n = tid & 15;
    if (c < RNN_C) {
      float sum = b_p[c];
      for (int k = 0; k < RNN_H; ++k) {
        const int s  = k >> 6;
        const int ko = k & 63;
        const int g2 = (ko >> 2) & 3;
        const int j  = (ko & 3) + 4*(ko >> 4);     // byte 0..15 across halves
        const int half = j >> 3, jj = j & 7;
        const signed char* base = (const signed char*)&hbuf[0][s][half][16*g2 + n];
        const int qv = 256*(int)base[jj] + (int)base[8 + jj];
        sum = __builtin_fmaf(w_ph[c*RNN_H + k], qv * (1.0f/QSW), sum);
      }
      out[(size_t)(n0 + n)*RNN_C + c] = sum;
    }
  }
}

extern "C" void kernel_launch(void* const* d_in, const int* in_sizes, int n_in,
                              void* d_out, int out_size, void* d_ws, size_t ws_size,
                              hipStream_t stream) {
  (void)in_sizes; (void)n_in; (void)out_size; (void)d_ws; (void)ws_size;
  const float* x    = (const float*)d_in[0];
  const float* w_hx = (const float*)d_in[1];
  const float* w_hh = (const float*)d_in[2];
  const float* b_h  = (const float*)d_in[3];
  const float* w_ph = (const float*)d_in[4];
  const float* b_p  = (const float*)d_in[5];
  float* out = (float*)d_out;
  rnn_fused<<<dim3(RNN_B/BLK_N), dim3(256), 0, stream>>>(x, w_hx, w_hh, b_h, w_ph, b_p, out);
}